// Round 5
// baseline (562.035 us; speedup 1.0000x reference)
//
#include <hip/hip_runtime.h>

#define M_PATCH 676
#define K_DIM   384
#define N_LIB   100000
#define BM      128
#define BN      128
#define NCH     782           // ceil(100000/128)
#define MTILES  6
#define M_PAD   (MTILES*BM)   // 768
#define N_PAD   (NCH*BN)      // 100096
#define XCHUNK  98            // chunks per XCD (8*98 = 784 >= 782)
#define GRID_GEMM (8*XCHUNK*MTILES)   // 4704
#define NTOPB   1563          // ceil(100000/64)
#define NCAND   (NTOPB*3)
#define IMG     224
#define FMAP    26
#define KS      33
#define KHALF   16

typedef __attribute__((ext_vector_type(4))) float  f32x4;
typedef __attribute__((ext_vector_type(8))) short  short8;
typedef unsigned long long ull;

static __device__ __forceinline__ unsigned short f2bf(float f) {
  unsigned u = __float_as_uint(f);
  u = u + 0x7FFFu + ((u >> 16) & 1u);   // RNE; inputs finite
  return (unsigned short)(u >> 16);
}

static __device__ __forceinline__ ull shfl_xor_u64(ull v, int m) {
  unsigned lo = (unsigned)v, hi = (unsigned)(v >> 32);
  lo = __shfl_xor(lo, m, 64);
  hi = __shfl_xor(hi, m, 64);
  return ((ull)hi << 32) | lo;
}

static __device__ __forceinline__ ull umin64(ull a, ull b) { return a < b ? a : b; }
static __device__ __forceinline__ ull umax64(ull a, ull b) { return a > b ? a : b; }

static __device__ __forceinline__ void gld16(const unsigned short* g, unsigned short* l) {
  __builtin_amdgcn_global_load_lds(
      (const __attribute__((address_space(1))) void*)g,
      (__attribute__((address_space(3))) void*)l, 16, 0, 0);
}

// ---------------- K1: row norms + bf16 conversion (float2/ushort2 vectorized) ------------
// grid: (N_PAD + M_PAD)/4 blocks x 256; one wave per row. (round-3 kernel, measured)
__global__ void pc_norms_cvt_kernel(const float* __restrict__ patch, const float* __restrict__ lib,
                                    float* __restrict__ y2, float* __restrict__ x2,
                                    unsigned short* __restrict__ Abf, unsigned short* __restrict__ Bbf) {
  const int w = threadIdx.x >> 6, lane = threadIdx.x & 63;
  const long r = (long)blockIdx.x * 4 + w;
  if (r < N_PAD) {
    float s;
    if (r < N_LIB) {
      const float2* p = (const float2*)(lib + r * K_DIM);
      ushort2* q = (ushort2*)(Bbf + r * K_DIM);
      float2 v[3];
      s = 0.f;
      #pragma unroll
      for (int j = 0; j < 3; ++j) { v[j] = p[lane + 64 * j]; s += v[j].x * v[j].x + v[j].y * v[j].y; }
      #pragma unroll
      for (int j = 0; j < 3; ++j) q[lane + 64 * j] = make_ushort2(f2bf(v[j].x), f2bf(v[j].y));
      #pragma unroll
      for (int m = 1; m < 64; m <<= 1) s += __shfl_xor(s, m, 64);
    } else {
      s = __builtin_inff();
      ushort2* q = (ushort2*)(Bbf + r * K_DIM);
      #pragma unroll
      for (int j = 0; j < 3; ++j) q[lane + 64 * j] = make_ushort2(0, 0);
    }
    if (lane == 0) y2[r] = s;
  } else {
    const long pr = r - N_PAD;
    if (pr < M_PATCH) {
      const float2* p = (const float2*)(patch + pr * K_DIM);
      ushort2* q = (ushort2*)(Abf + pr * K_DIM);
      float2 v[3]; float s = 0.f;
      #pragma unroll
      for (int j = 0; j < 3; ++j) { v[j] = p[lane + 64 * j]; s += v[j].x * v[j].x + v[j].y * v[j].y; }
      #pragma unroll
      for (int j = 0; j < 3; ++j) q[lane + 64 * j] = make_ushort2(f2bf(v[j].x), f2bf(v[j].y));
      #pragma unroll
      for (int m = 1; m < 64; m <<= 1) s += __shfl_xor(s, m, 64);
      if (lane == 0) x2[pr] = s;
    } else if (pr < M_PAD) {
      ushort2* q = (ushort2*)(Abf + pr * K_DIM);
      #pragma unroll
      for (int j = 0; j < 3; ++j) q[lane + 64 * j] = make_ushort2(0, 0);
    }
  }
}

// ---------------- K2: bf16 MFMA GEMM, XCD-partitioned grid, BK=64, fused min -------------
// (round-3 kernel, measured 117us.) LDS staging via global_load_lds, XOR swizzle.
__launch_bounds__(256, 4)
__global__ void pc_gemm_min_bf16_kernel(const unsigned short* __restrict__ Abf,
                                        const unsigned short* __restrict__ Bbf,
                                        const float* __restrict__ x2g, const float* __restrict__ y2g,
                                        ull* __restrict__ partial) {
  __shared__ unsigned short As[2][BM * 32];
  __shared__ unsigned short Bs[2][BN * 32];
  __shared__ float x2s[BM];
  __shared__ float y2s[BN];
  __shared__ ull red[BM * 2];

  const int l = blockIdx.x;
  const int xcd = l & 7, slot = l >> 3;
  const int chunk = xcd * XCHUNK + slot / MTILES;
  const int mtile = slot % MTILES;
  if (chunk >= NCH) return;

  const int t = threadIdx.x;
  const int m0 = mtile * BM;
  const int n0 = chunk * BN;
  const int wid = t >> 6, lane = t & 63;

  if (t < BM) {
    const int gm = m0 + t;
    x2s[t] = (gm < M_PATCH) ? x2g[gm] : 0.f;
    y2s[t] = y2g[n0 + t];
  }

  const int srow   = (wid << 4) + (lane >> 2);
  const int spiece = (lane & 3) ^ ((lane >> 4) & 3);
  const unsigned short* gA0 = Abf + (size_t)(m0 + srow) * K_DIM + spiece * 8;
  const unsigned short* gA1 = gA0 + (size_t)64 * K_DIM;
  const unsigned short* gB0 = Bbf + (size_t)(n0 + srow) * K_DIM + spiece * 8;
  const unsigned short* gB1 = gB0 + (size_t)64 * K_DIM;

  f32x4 acc[4][4];
  #pragma unroll
  for (int i = 0; i < 4; ++i)
    #pragma unroll
    for (int j = 0; j < 4; ++j) acc[i][j] = (f32x4){0.f, 0.f, 0.f, 0.f};

  const int wm = wid >> 1, wn = wid & 1;
  const int quad = lane >> 4, l15 = lane & 15;
  const int poff = (quad ^ ((l15 >> 2) & 3)) * 8;

  for (int ks = 0; ks < K_DIM / 64; ++ks) {
    __syncthreads();
    #pragma unroll
    for (int h = 0; h < 2; ++h) {
      const int ko = ks * 64 + h * 32;
      gld16(gA0 + ko, &As[h][wid * 512]);
      gld16(gA1 + ko, &As[h][(wid + 4) * 512]);
      gld16(gB0 + ko, &Bs[h][wid * 512]);
      gld16(gB1 + ko, &Bs[h][(wid + 4) * 512]);
    }
    __builtin_amdgcn_s_waitcnt(0);
    __syncthreads();

    #pragma unroll
    for (int h = 0; h < 2; ++h) {
      short8 af[4], bf[4];
      #pragma unroll
      for (int mi = 0; mi < 4; ++mi)
        af[mi] = *(const short8*)&As[h][(wm * 64 + mi * 16 + l15) * 32 + poff];
      #pragma unroll
      for (int ni = 0; ni < 4; ++ni)
        bf[ni] = *(const short8*)&Bs[h][(wn * 64 + ni * 16 + l15) * 32 + poff];
      #pragma unroll
      for (int mi = 0; mi < 4; ++mi)
        #pragma unroll
        for (int ni = 0; ni < 4; ++ni)
          acc[mi][ni] = __builtin_amdgcn_mfma_f32_16x16x32_bf16(af[mi], bf[ni], acc[mi][ni], 0, 0, 0);
    }
  }

  #pragma unroll
  for (int mi = 0; mi < 4; ++mi) {
    #pragma unroll
    for (int r = 0; r < 4; ++r) {
      const int row_l = wm * 64 + mi * 16 + quad * 4 + r;
      const float xs = x2s[row_l];
      ull kmin = ~0ull;
      #pragma unroll
      for (int ni = 0; ni < 4; ++ni) {
        const int col_l = wn * 64 + ni * 16 + l15;
        float d2 = xs + y2s[col_l] - 2.0f * acc[mi][ni][r];
        d2 = fmaxf(d2, 0.0f);
        const ull key = ((ull)__float_as_uint(d2) << 32) | (unsigned)(n0 + col_l);
        kmin = umin64(kmin, key);
      }
      #pragma unroll
      for (int off = 1; off < 16; off <<= 1) kmin = umin64(kmin, shfl_xor_u64(kmin, off));
      if (l15 == 0) red[row_l * 2 + wn] = kmin;
    }
  }
  __syncthreads();
  if (t < BM) {
    const ull k = umin64(red[t * 2], red[t * 2 + 1]);
    partial[(size_t)chunk * M_PAD + m0 + t] = k;   // coalesced 1KB per block
  }
}

// ---------------- K3: partial reduce (48 blocks) + last-block select ---------------------
__global__ void pc_reduce_kernel(const ull* __restrict__ partial, ull* __restrict__ stage1,
                                 float* __restrict__ minval, unsigned* __restrict__ minidx,
                                 unsigned* __restrict__ scal) {
  const int b = blockIdx.x, mt = b >> 3, gp = b & 7;
  const int t = threadIdx.x;           // 128
  const int c0 = gp * XCHUNK;
  ull k = ~0ull;
  #pragma unroll 7
  for (int i = 0; i < XCHUNK; ++i)
    k = umin64(k, partial[(size_t)(c0 + i) * M_PAD + mt * 128 + t]);
  stage1[(size_t)(mt * 128 + t) * 8 + gp] = k;
  __threadfence();
  __syncthreads();
  __shared__ unsigned rank_s;
  if (t == 0) rank_s = atomicAdd(&scal[8], 1u);
  __syncthreads();
  if (rank_s != 47) return;
  __threadfence();

  ull best = 0ull;
  for (int m = t; m < M_PATCH; m += 128) {
    ull kk = ~0ull;
    #pragma unroll
    for (int g = 0; g < 8; ++g) kk = umin64(kk, stage1[(size_t)m * 8 + g]);
    const float d = sqrtf(fmaxf(__uint_as_float((unsigned)(kk >> 32)), 0.f));
    minval[m] = d;
    minidx[m] = (unsigned)kk;
    best = umax64(best, ((ull)__float_as_uint(d) << 32) | (0xFFFFFFFFu - (unsigned)m));
  }
  #pragma unroll
  for (int off = 1; off < 64; off <<= 1) best = umax64(best, shfl_xor_u64(best, off));
  __shared__ ull sh[2];
  if ((t & 63) == 0) sh[t >> 6] = best;
  __syncthreads();
  if (t == 0) {
    best = umax64(sh[0], sh[1]);
    const unsigned m = 0xFFFFFFFFu - (unsigned)best;
    scal[0] = m;                      // s_idx
    scal[1] = (unsigned)(best >> 32); // s_star bits
    scal[2] = minidx[m];              // m_star row
  }
}

// ---------------- K4: fp32 w_dist^2 (4-row ILP batches) + top3 + merge + score -----------
__global__ void pc_wdist_kernel(const float* __restrict__ patch, const float* __restrict__ lib,
                                unsigned* __restrict__ scal, ull* __restrict__ cand,
                                float* __restrict__ out) {
  __shared__ ull keys[64];
  const int t = threadIdx.x, w = t >> 6, lane = t & 63;
  const float2* ms = (const float2*)(lib + (size_t)scal[2] * K_DIM);
  float2 msv[3];
  #pragma unroll
  for (int j = 0; j < 3; ++j) msv[j] = ms[lane + 64 * j];
  const long r0 = (long)blockIdx.x * 64 + w * 16;

  // 4 batches of 4 rows: 12 loads in flight, 4 independent reduction chains.
  #pragma unroll
  for (int b = 0; b < 4; ++b) {
    const long rb = r0 + b * 4;
    float2 v[4][3];
    #pragma unroll
    for (int i = 0; i < 4; ++i) {
      const long r = rb + i;
      const float2* p = (const float2*)(lib + (r < N_LIB ? r : 0) * K_DIM);
      #pragma unroll
      for (int j = 0; j < 3; ++j) v[i][j] = p[lane + 64 * j];
    }
    float s[4];
    #pragma unroll
    for (int i = 0; i < 4; ++i) {
      s[i] = 0.f;
      #pragma unroll
      for (int j = 0; j < 3; ++j) {
        const float dx = v[i][j].x - msv[j].x, dy = v[i][j].y - msv[j].y;
        s[i] += dx * dx + dy * dy;
      }
    }
    #pragma unroll
    for (int m = 1; m < 64; m <<= 1) {
      #pragma unroll
      for (int i = 0; i < 4; ++i) s[i] += __shfl_xor(s[i], m, 64);
    }
    if (lane == 0) {
      #pragma unroll
      for (int i = 0; i < 4; ++i) {
        const long r = rb + i;
        keys[w * 16 + b * 4 + i] =
            (r < N_LIB) ? (((ull)__float_as_uint(s[i]) << 32) | (unsigned)r) : ~0ull;
      }
    }
  }
  __syncthreads();
  if (t == 0) {
    ull picks[3];
    #pragma unroll
    for (int p = 0; p < 3; ++p) {
      ull bestk = ~0ull;
      for (int i = 0; i < 64; ++i) {
        const ull k = keys[i];
        if ((p > 0 && k == picks[0]) || (p > 1 && k == picks[1])) continue;
        bestk = umin64(bestk, k);
      }
      picks[p] = bestk;
      cand[(long)blockIdx.x * 3 + p] = bestk;
    }
  }
  __threadfence();
  __syncthreads();
  __shared__ unsigned rank_s;
  if (t == 0) rank_s = atomicAdd(&scal[9], 1u);
  __syncthreads();
  if (rank_s != NTOPB - 1) return;
  __threadfence();

  // last block: global first-min top-3 over candidates (matches lax.top_k ties)
  __shared__ ull shm[4];
  __shared__ ull picks_s[3];
  for (int p = 0; p < 3; ++p) {
    const ull e0 = (p > 0) ? picks_s[0] : 0ull;
    const ull e1 = (p > 1) ? picks_s[1] : 0ull;
    ull k = ~0ull;
    for (int n = t; n < NCAND; n += 256) {
      const ull c = cand[n];
      if ((p > 0 && c == e0) || (p > 1 && c == e1)) continue;
      k = umin64(k, c);
    }
    #pragma unroll
    for (int off = 1; off < 64; off <<= 1) k = umin64(k, shfl_xor_u64(k, off));
    if ((t & 63) == 0) shm[t >> 6] = k;
    __syncthreads();
    if (t == 0) {
      #pragma unroll
      for (int ww = 1; ww < 4; ++ww) k = umin64(k, shm[ww]);
      picks_s[p] = k;
    }
    __syncthreads();
  }
  // exact fp32 distances m_test vs the 2nd/3rd neighbors
  __shared__ float sh2[2];
  if (w < 2) {
    const unsigned nn = (unsigned)picks_s[1 + w];
    const float* mt2 = patch + (size_t)scal[0] * K_DIM;
    const float* pv  = lib + (size_t)nn * K_DIM;
    float s = 0.f;
    #pragma unroll
    for (int j = 0; j < 6; ++j) { const float d = mt2[lane + 64 * j] - pv[lane + 64 * j]; s += d * d; }
    #pragma unroll
    for (int m = 1; m < 64; m <<= 1) s += __shfl_xor(s, m, 64);
    if (lane == 0) sh2[w] = s;
  }
  __syncthreads();
  if (t == 0) {
    const float D = sqrtf((float)K_DIM);
    const float s_star = __uint_as_float(scal[1]);
    const float a = sqrtf(sh2[0]), b = sqrtf(sh2[1]);
    const float wgt = 1.f - expf(s_star / D) / (expf(a / D) + expf(b / D));
    out[0] = wgt * s_star;
  }
}

// ---------------- K5: fused bilinear 26->224 + separable 33-tap gaussian -----------------
static __device__ __forceinline__ int pc_refl(int i) {
  return i < 0 ? -i : (i >= IMG ? 2 * IMG - 2 - i : i);
}

__global__ void pc_map_kernel(const float* __restrict__ minval, float* __restrict__ outmap) {
  __shared__ double kd[KS + 1];
  __shared__ float kf[KS];
  __shared__ float smap[FMAP * FMAP];
  __shared__ float by[IMG];
  const int t = threadIdx.x;          // 256
  const int y = blockIdx.x;           // 224
  if (t < KS) { const double xx = (double)(t - KHALF) / 4.0; kd[t] = exp(-0.5 * xx * xx); }
  for (int i = t; i < FMAP * FMAP; i += 256) smap[i] = minval[i];
  __syncthreads();
  if (t == 0) { double s = 0.0; for (int i = 0; i < KS; ++i) s += kd[i]; kd[KS] = s; }
  __syncthreads();
  if (t < KS) kf[t] = (float)(kd[t] / kd[KS]);
  __syncthreads();

  const float scale = (float)FMAP / (float)IMG;
  if (t < IMG) {
    const float fx = ((float)t + 0.5f) * scale - 0.5f;
    const int ix0 = (int)floorf(fx); const float tx = fx - (float)ix0;
    const int x0 = min(max(ix0, 0), FMAP - 1), x1 = min(max(ix0 + 1, 0), FMAP - 1);
    float s = 0.f;
    #pragma unroll
    for (int j = 0; j < KS; ++j) {
      const int yy = pc_refl(y + j - KHALF);
      const float fy = ((float)yy + 0.5f) * scale - 0.5f;
      const int iy0 = (int)floorf(fy); const float ty = fy - (float)iy0;
      const int y0 = min(max(iy0, 0), FMAP - 1), y1 = min(max(iy0 + 1, 0), FMAP - 1);
      const float v00 = smap[y0 * FMAP + x0], v01 = smap[y0 * FMAP + x1];
      const float v10 = smap[y1 * FMAP + x0], v11 = smap[y1 * FMAP + x1];
      const float v0 = v00 + (v01 - v00) * tx;
      const float v1 = v10 + (v11 - v10) * tx;
      s += kf[j] * (v0 + (v1 - v0) * ty);
    }
    by[t] = s;
  }
  __syncthreads();
  if (t < IMG) {
    float s = 0.f;
    #pragma unroll
    for (int i = 0; i < KS; ++i) s += kf[i] * by[pc_refl(t + i - KHALF)];
    outmap[y * IMG + t] = s;
  }
}

extern "C" void kernel_launch(void* const* d_in, const int* in_sizes, int n_in,
                              void* d_out, int out_size, void* d_ws, size_t ws_size,
                              hipStream_t stream) {
  const float* patch = (const float*)d_in[0];
  const float* lib   = (const float*)d_in[1];
  float* out = (float*)d_out;

  char* p = (char*)d_ws;
  auto take = [&](size_t n) { char* q = p; p += (n + 511) & ~(size_t)511; return q; };
  float* y2        = (float*)take((size_t)N_PAD * 4);
  float* x2        = (float*)take((size_t)M_PAD * 4);
  ull* partial     = (ull*)take((size_t)(NCH + 2) * M_PAD * 8);   // +2 pad chunks
  ull* stage1      = (ull*)take((size_t)M_PAD * 8 * 8);
  float* minval    = (float*)take((size_t)M_PATCH * 4);
  unsigned* minidx = (unsigned*)take((size_t)M_PATCH * 4);
  unsigned* scal   = (unsigned*)take(256);                        // [0..7] results, [8..9] counters
  ull* cand        = (ull*)take((size_t)NCAND * 8);
  unsigned short* Abf = (unsigned short*)take((size_t)M_PAD * K_DIM * 2);
  unsigned short* Bbf = (unsigned short*)take((size_t)N_PAD * K_DIM * 2);
  (void)in_sizes; (void)n_in; (void)out_size; (void)ws_size;

  hipMemsetAsync(scal, 0, 64, stream);
  hipMemsetAsync(partial + (size_t)NCH * M_PAD, 0xFF, 2 * M_PAD * 8, stream);

  const int norm_rows = N_PAD + M_PAD;  // 100864
  pc_norms_cvt_kernel<<<(norm_rows + 3) / 4, 256, 0, stream>>>(patch, lib, y2, x2, Abf, Bbf);
  pc_gemm_min_bf16_kernel<<<GRID_GEMM, 256, 0, stream>>>(Abf, Bbf, x2, y2, partial);
  pc_reduce_kernel<<<48, 128, 0, stream>>>(partial, stage1, minval, minidx, scal);
  pc_wdist_kernel<<<NTOPB, 256, 0, stream>>>(patch, lib, scal, cand, out);
  pc_map_kernel<<<IMG, 256, 0, stream>>>(minval, out + 1);
}

// Round 6
// 385.655 us; speedup vs baseline: 1.4574x; 1.4574x over previous
//
#include <hip/hip_runtime.h>

#define M_PATCH 676
#define K_DIM   384
#define N_LIB   100000
#define BM      128
#define BN      128
#define NCH     782           // ceil(100000/128)
#define MTILES  6
#define M_PAD   (MTILES*BM)   // 768
#define N_PAD   (NCH*BN)      // 100096
#define XCHUNK  98            // chunks per XCD (8*98 = 784 >= 782)
#define GRID_GEMM (8*XCHUNK*MTILES)   // 4704
#define NTOPB   1563          // ceil(100000/64)
#define NCAND   (NTOPB*3)
#define IMG     224
#define FMAP    26
#define KS      33
#define KHALF   16

typedef __attribute__((ext_vector_type(4))) float  f32x4;
typedef __attribute__((ext_vector_type(8))) short  short8;
typedef unsigned long long ull;

static __device__ __forceinline__ unsigned short f2bf(float f) {
  unsigned u = __float_as_uint(f);
  u = u + 0x7FFFu + ((u >> 16) & 1u);   // RNE; inputs finite
  return (unsigned short)(u >> 16);
}

static __device__ __forceinline__ ull shfl_xor_u64(ull v, int m) {
  unsigned lo = (unsigned)v, hi = (unsigned)(v >> 32);
  lo = __shfl_xor(lo, m, 64);
  hi = __shfl_xor(hi, m, 64);
  return ((ull)hi << 32) | lo;
}

static __device__ __forceinline__ ull umin64(ull a, ull b) { return a < b ? a : b; }
static __device__ __forceinline__ ull umax64(ull a, ull b) { return a > b ? a : b; }

static __device__ __forceinline__ void gld16(const unsigned short* g, unsigned short* l) {
  __builtin_amdgcn_global_load_lds(
      (const __attribute__((address_space(1))) void*)g,
      (__attribute__((address_space(3))) void*)l, 16, 0, 0);
}

// ---------------- K1: row norms + bf16 conversion (float2/ushort2 vectorized) ------------
__global__ void pc_norms_cvt_kernel(const float* __restrict__ patch, const float* __restrict__ lib,
                                    float* __restrict__ y2, float* __restrict__ x2,
                                    unsigned short* __restrict__ Abf, unsigned short* __restrict__ Bbf) {
  const int w = threadIdx.x >> 6, lane = threadIdx.x & 63;
  const long r = (long)blockIdx.x * 4 + w;
  if (r < N_PAD) {
    float s;
    if (r < N_LIB) {
      const float2* p = (const float2*)(lib + r * K_DIM);
      ushort2* q = (ushort2*)(Bbf + r * K_DIM);
      float2 v[3];
      s = 0.f;
      #pragma unroll
      for (int j = 0; j < 3; ++j) { v[j] = p[lane + 64 * j]; s += v[j].x * v[j].x + v[j].y * v[j].y; }
      #pragma unroll
      for (int j = 0; j < 3; ++j) q[lane + 64 * j] = make_ushort2(f2bf(v[j].x), f2bf(v[j].y));
      #pragma unroll
      for (int m = 1; m < 64; m <<= 1) s += __shfl_xor(s, m, 64);
    } else {
      s = __builtin_inff();
      ushort2* q = (ushort2*)(Bbf + r * K_DIM);
      #pragma unroll
      for (int j = 0; j < 3; ++j) q[lane + 64 * j] = make_ushort2(0, 0);
    }
    if (lane == 0) y2[r] = s;
  } else {
    const long pr = r - N_PAD;
    if (pr < M_PATCH) {
      const float2* p = (const float2*)(patch + pr * K_DIM);
      ushort2* q = (ushort2*)(Abf + pr * K_DIM);
      float2 v[3]; float s = 0.f;
      #pragma unroll
      for (int j = 0; j < 3; ++j) { v[j] = p[lane + 64 * j]; s += v[j].x * v[j].x + v[j].y * v[j].y; }
      #pragma unroll
      for (int j = 0; j < 3; ++j) q[lane + 64 * j] = make_ushort2(f2bf(v[j].x), f2bf(v[j].y));
      #pragma unroll
      for (int m = 1; m < 64; m <<= 1) s += __shfl_xor(s, m, 64);
      if (lane == 0) x2[pr] = s;
    } else if (pr < M_PAD) {
      ushort2* q = (ushort2*)(Abf + pr * K_DIM);
      #pragma unroll
      for (int j = 0; j < 3; ++j) q[lane + 64 * j] = make_ushort2(0, 0);
    }
  }
}

// ---------------- K2: bf16 MFMA GEMM, XCD-partitioned grid, BK=64, fused min -------------
__launch_bounds__(256, 4)
__global__ void pc_gemm_min_bf16_kernel(const unsigned short* __restrict__ Abf,
                                        const unsigned short* __restrict__ Bbf,
                                        const float* __restrict__ x2g, const float* __restrict__ y2g,
                                        ull* __restrict__ partial) {
  __shared__ unsigned short As[2][BM * 32];
  __shared__ unsigned short Bs[2][BN * 32];
  __shared__ float x2s[BM];
  __shared__ float y2s[BN];
  __shared__ ull red[BM * 2];

  const int l = blockIdx.x;
  const int xcd = l & 7, slot = l >> 3;
  const int chunk = xcd * XCHUNK + slot / MTILES;
  const int mtile = slot % MTILES;
  if (chunk >= NCH) return;

  const int t = threadIdx.x;
  const int m0 = mtile * BM;
  const int n0 = chunk * BN;
  const int wid = t >> 6, lane = t & 63;

  if (t < BM) {
    const int gm = m0 + t;
    x2s[t] = (gm < M_PATCH) ? x2g[gm] : 0.f;
    y2s[t] = y2g[n0 + t];
  }

  const int srow   = (wid << 4) + (lane >> 2);
  const int spiece = (lane & 3) ^ ((lane >> 4) & 3);
  const unsigned short* gA0 = Abf + (size_t)(m0 + srow) * K_DIM + spiece * 8;
  const unsigned short* gA1 = gA0 + (size_t)64 * K_DIM;
  const unsigned short* gB0 = Bbf + (size_t)(n0 + srow) * K_DIM + spiece * 8;
  const unsigned short* gB1 = gB0 + (size_t)64 * K_DIM;

  f32x4 acc[4][4];
  #pragma unroll
  for (int i = 0; i < 4; ++i)
    #pragma unroll
    for (int j = 0; j < 4; ++j) acc[i][j] = (f32x4){0.f, 0.f, 0.f, 0.f};

  const int wm = wid >> 1, wn = wid & 1;
  const int quad = lane >> 4, l15 = lane & 15;
  const int poff = (quad ^ ((l15 >> 2) & 3)) * 8;

  for (int ks = 0; ks < K_DIM / 64; ++ks) {
    __syncthreads();
    #pragma unroll
    for (int h = 0; h < 2; ++h) {
      const int ko = ks * 64 + h * 32;
      gld16(gA0 + ko, &As[h][wid * 512]);
      gld16(gA1 + ko, &As[h][(wid + 4) * 512]);
      gld16(gB0 + ko, &Bs[h][wid * 512]);
      gld16(gB1 + ko, &Bs[h][(wid + 4) * 512]);
    }
    __builtin_amdgcn_s_waitcnt(0);
    __syncthreads();

    #pragma unroll
    for (int h = 0; h < 2; ++h) {
      short8 af[4], bf[4];
      #pragma unroll
      for (int mi = 0; mi < 4; ++mi)
        af[mi] = *(const short8*)&As[h][(wm * 64 + mi * 16 + l15) * 32 + poff];
      #pragma unroll
      for (int ni = 0; ni < 4; ++ni)
        bf[ni] = *(const short8*)&Bs[h][(wn * 64 + ni * 16 + l15) * 32 + poff];
      #pragma unroll
      for (int mi = 0; mi < 4; ++mi)
        #pragma unroll
        for (int ni = 0; ni < 4; ++ni)
          acc[mi][ni] = __builtin_amdgcn_mfma_f32_16x16x32_bf16(af[mi], bf[ni], acc[mi][ni], 0, 0, 0);
    }
  }

  #pragma unroll
  for (int mi = 0; mi < 4; ++mi) {
    #pragma unroll
    for (int r = 0; r < 4; ++r) {
      const int row_l = wm * 64 + mi * 16 + quad * 4 + r;
      const float xs = x2s[row_l];
      ull kmin = ~0ull;
      #pragma unroll
      for (int ni = 0; ni < 4; ++ni) {
        const int col_l = wn * 64 + ni * 16 + l15;
        float d2 = xs + y2s[col_l] - 2.0f * acc[mi][ni][r];
        d2 = fmaxf(d2, 0.0f);
        const ull key = ((ull)__float_as_uint(d2) << 32) | (unsigned)(n0 + col_l);
        kmin = umin64(kmin, key);
      }
      #pragma unroll
      for (int off = 1; off < 16; off <<= 1) kmin = umin64(kmin, shfl_xor_u64(kmin, off));
      if (l15 == 0) red[row_l * 2 + wn] = kmin;
    }
  }
  __syncthreads();
  if (t < BM) {
    const ull k = umin64(red[t * 2], red[t * 2 + 1]);
    partial[(size_t)chunk * M_PAD + m0 + t] = k;   // coalesced 1KB per block
  }
}

// ---------------- K3: partial reduce (48 blocks) + last-block select ---------------------
__global__ void pc_reduce_kernel(const ull* __restrict__ partial, ull* __restrict__ stage1,
                                 float* __restrict__ minval, unsigned* __restrict__ minidx,
                                 unsigned* __restrict__ scal) {
  const int b = blockIdx.x, mt = b >> 3, gp = b & 7;
  const int t = threadIdx.x;           // 128
  const int c0 = gp * XCHUNK;
  ull k = ~0ull;
  #pragma unroll 7
  for (int i = 0; i < XCHUNK; ++i)
    k = umin64(k, partial[(size_t)(c0 + i) * M_PAD + mt * 128 + t]);
  stage1[(size_t)(mt * 128 + t) * 8 + gp] = k;
  __threadfence();
  __syncthreads();
  __shared__ unsigned rank_s;
  if (t == 0) rank_s = atomicAdd(&scal[8], 1u);
  __syncthreads();
  if (rank_s != 47) return;
  __threadfence();

  ull best = 0ull;
  for (int m = t; m < M_PATCH; m += 128) {
    ull kk = ~0ull;
    #pragma unroll
    for (int g = 0; g < 8; ++g) kk = umin64(kk, stage1[(size_t)m * 8 + g]);
    const float d = sqrtf(fmaxf(__uint_as_float((unsigned)(kk >> 32)), 0.f));
    minval[m] = d;
    minidx[m] = (unsigned)kk;
    best = umax64(best, ((ull)__float_as_uint(d) << 32) | (0xFFFFFFFFu - (unsigned)m));
  }
  #pragma unroll
  for (int off = 1; off < 64; off <<= 1) best = umax64(best, shfl_xor_u64(best, off));
  __shared__ ull sh[2];
  if ((t & 63) == 0) sh[t >> 6] = best;
  __syncthreads();
  if (t == 0) {
    best = umax64(sh[0], sh[1]);
    const unsigned m = 0xFFFFFFFFu - (unsigned)best;
    scal[0] = m;                      // s_idx
    scal[1] = (unsigned)(best >> 32); // s_star bits
    scal[2] = minidx[m];              // m_star row
  }
}

// ---------------- K4: bf16 GEMV w_dist^2 scan + per-block top3 (NO fences/atomics) -------
// d2(r) = y2[star] + y2[r] - 2*dot_bf16(star, r); ordering-only (exact dists recomputed
// for the chosen indices in the merge kernel). Star row stays unique top-1 (d2 ~ 0).
__global__ void pc_wdist_scan_kernel(const unsigned short* __restrict__ Bbf,
                                     const float* __restrict__ y2,
                                     const unsigned* __restrict__ scal,
                                     ull* __restrict__ cand) {
  __shared__ ull keys[64];
  const int t = threadIdx.x, w = t >> 6, lane = t & 63;
  const unsigned star = scal[2];
  const float y2star = y2[star];
  const unsigned* msp = (const unsigned*)(Bbf + (size_t)star * K_DIM);
  float msl[3], msh[3];
  #pragma unroll
  for (int j = 0; j < 3; ++j) {
    const unsigned u = msp[lane + 64 * j];
    msl[j] = __uint_as_float(u << 16);
    msh[j] = __uint_as_float(u & 0xFFFF0000u);
  }
  const long r0 = (long)blockIdx.x * 64 + w * 16;
  for (int i = 0; i < 16; ++i) {
    const long r = r0 + i;
    ull key = ~0ull;
    if (r < N_LIB) {
      const unsigned* p = (const unsigned*)(Bbf + (size_t)r * K_DIM);
      float s = 0.f;
      #pragma unroll
      for (int j = 0; j < 3; ++j) {
        const unsigned u = p[lane + 64 * j];
        s += msl[j] * __uint_as_float(u << 16) + msh[j] * __uint_as_float(u & 0xFFFF0000u);
      }
      #pragma unroll
      for (int m = 1; m < 64; m <<= 1) s += __shfl_xor(s, m, 64);
      const float d2 = fmaxf(y2star + y2[r] - 2.0f * s, 0.0f);
      key = ((ull)__float_as_uint(d2) << 32) | (unsigned)r;
    }
    if (lane == 0) keys[w * 16 + i] = key;
  }
  __syncthreads();
  if (t == 0) {
    ull picks[3];
    #pragma unroll
    for (int p = 0; p < 3; ++p) {
      ull best = ~0ull;
      for (int i = 0; i < 64; ++i) {
        const ull k = keys[i];
        if ((p > 0 && k == picks[0]) || (p > 1 && k == picks[1])) continue;
        best = umin64(best, k);
      }
      picks[p] = best;
      cand[(long)blockIdx.x * 3 + p] = best;
    }
  }
}

// ---------------- K5: merge candidates (first-min top-3) + exact dists + score -----------
__global__ void pc_merge_final_kernel(const float* __restrict__ patch, const float* __restrict__ lib,
                                      const unsigned* __restrict__ scal, const ull* __restrict__ cand,
                                      float* __restrict__ out) {
  __shared__ ull shm[16];
  __shared__ ull picks_s[3];
  const int t = threadIdx.x, w = t >> 6, lane = t & 63;  // 1024 threads
  for (int p = 0; p < 3; ++p) {
    const ull e0 = (p > 0) ? picks_s[0] : 0ull;
    const ull e1 = (p > 1) ? picks_s[1] : 0ull;
    ull k = ~0ull;
    for (int n = t; n < NCAND; n += 1024) {
      const ull c = cand[n];
      if ((p > 0 && c == e0) || (p > 1 && c == e1)) continue;
      k = umin64(k, c);
    }
    #pragma unroll
    for (int off = 1; off < 64; off <<= 1) k = umin64(k, shfl_xor_u64(k, off));
    if ((t & 63) == 0) shm[t >> 6] = k;
    __syncthreads();
    if (t == 0) {
      #pragma unroll
      for (int ww = 1; ww < 16; ++ww) k = umin64(k, shm[ww]);
      picks_s[p] = k;
    }
    __syncthreads();
  }
  // exact fp32 distances m_test vs the 2nd/3rd neighbors
  __shared__ float sh2[2];
  if (w < 2) {
    const unsigned nn = (unsigned)picks_s[1 + w];
    const float* mt2 = patch + (size_t)scal[0] * K_DIM;
    const float* pv  = lib + (size_t)nn * K_DIM;
    float s = 0.f;
    #pragma unroll
    for (int j = 0; j < 6; ++j) { const float d = mt2[lane + 64 * j] - pv[lane + 64 * j]; s += d * d; }
    #pragma unroll
    for (int m = 1; m < 64; m <<= 1) s += __shfl_xor(s, m, 64);
    if (lane == 0) sh2[w] = s;
  }
  __syncthreads();
  if (t == 0) {
    const float D = sqrtf((float)K_DIM);
    const float s_star = __uint_as_float(scal[1]);
    const float a = sqrtf(sh2[0]), b = sqrtf(sh2[1]);
    const float wgt = 1.f - expf(s_star / D) / (expf(a / D) + expf(b / D));
    out[0] = wgt * s_star;
  }
}

// ---------------- K6: fused bilinear 26->224 + separable 33-tap gaussian -----------------
static __device__ __forceinline__ int pc_refl(int i) {
  return i < 0 ? -i : (i >= IMG ? 2 * IMG - 2 - i : i);
}

__global__ void pc_map_kernel(const float* __restrict__ minval, float* __restrict__ outmap) {
  __shared__ double kd[KS + 1];
  __shared__ float kf[KS];
  __shared__ float smap[FMAP * FMAP];
  __shared__ float by[IMG];
  const int t = threadIdx.x;          // 256
  const int y = blockIdx.x;           // 224
  if (t < KS) { const double xx = (double)(t - KHALF) / 4.0; kd[t] = exp(-0.5 * xx * xx); }
  for (int i = t; i < FMAP * FMAP; i += 256) smap[i] = minval[i];
  __syncthreads();
  if (t == 0) { double s = 0.0; for (int i = 0; i < KS; ++i) s += kd[i]; kd[KS] = s; }
  __syncthreads();
  if (t < KS) kf[t] = (float)(kd[t] / kd[KS]);
  __syncthreads();

  const float scale = (float)FMAP / (float)IMG;
  if (t < IMG) {
    const float fx = ((float)t + 0.5f) * scale - 0.5f;
    const int ix0 = (int)floorf(fx); const float tx = fx - (float)ix0;
    const int x0 = min(max(ix0, 0), FMAP - 1), x1 = min(max(ix0 + 1, 0), FMAP - 1);
    float s = 0.f;
    #pragma unroll
    for (int j = 0; j < KS; ++j) {
      const int yy = pc_refl(y + j - KHALF);
      const float fy = ((float)yy + 0.5f) * scale - 0.5f;
      const int iy0 = (int)floorf(fy); const float ty = fy - (float)iy0;
      const int y0 = min(max(iy0, 0), FMAP - 1), y1 = min(max(iy0 + 1, 0), FMAP - 1);
      const float v00 = smap[y0 * FMAP + x0], v01 = smap[y0 * FMAP + x1];
      const float v10 = smap[y1 * FMAP + x0], v11 = smap[y1 * FMAP + x1];
      const float v0 = v00 + (v01 - v00) * tx;
      const float v1 = v10 + (v11 - v10) * tx;
      s += kf[j] * (v0 + (v1 - v0) * ty);
    }
    by[t] = s;
  }
  __syncthreads();
  if (t < IMG) {
    float s = 0.f;
    #pragma unroll
    for (int i = 0; i < KS; ++i) s += kf[i] * by[pc_refl(t + i - KHALF)];
    outmap[y * IMG + t] = s;
  }
}

extern "C" void kernel_launch(void* const* d_in, const int* in_sizes, int n_in,
                              void* d_out, int out_size, void* d_ws, size_t ws_size,
                              hipStream_t stream) {
  const float* patch = (const float*)d_in[0];
  const float* lib   = (const float*)d_in[1];
  float* out = (float*)d_out;

  char* p = (char*)d_ws;
  auto take = [&](size_t n) { char* q = p; p += (n + 511) & ~(size_t)511; return q; };
  float* y2        = (float*)take((size_t)N_PAD * 4);
  float* x2        = (float*)take((size_t)M_PAD * 4);
  ull* partial     = (ull*)take((size_t)(NCH + 2) * M_PAD * 8);   // +2 pad chunks
  ull* stage1      = (ull*)take((size_t)M_PAD * 8 * 8);
  float* minval    = (float*)take((size_t)M_PATCH * 4);
  unsigned* minidx = (unsigned*)take((size_t)M_PATCH * 4);
  unsigned* scal   = (unsigned*)take(256);                        // [0..7] results, [8] counter
  ull* cand        = (ull*)take((size_t)NCAND * 8);
  unsigned short* Abf = (unsigned short*)take((size_t)M_PAD * K_DIM * 2);
  unsigned short* Bbf = (unsigned short*)take((size_t)N_PAD * K_DIM * 2);
  (void)in_sizes; (void)n_in; (void)out_size; (void)ws_size;

  hipMemsetAsync(scal, 0, 64, stream);
  hipMemsetAsync(partial + (size_t)NCH * M_PAD, 0xFF, 2 * M_PAD * 8, stream);

  const int norm_rows = N_PAD + M_PAD;  // 100864
  pc_norms_cvt_kernel<<<(norm_rows + 3) / 4, 256, 0, stream>>>(patch, lib, y2, x2, Abf, Bbf);
  pc_gemm_min_bf16_kernel<<<GRID_GEMM, 256, 0, stream>>>(Abf, Bbf, x2, y2, partial);
  pc_reduce_kernel<<<48, 128, 0, stream>>>(partial, stage1, minval, minidx, scal);
  pc_wdist_scan_kernel<<<NTOPB, 256, 0, stream>>>(Bbf, y2, scal, cand);
  pc_merge_final_kernel<<<1, 1024, 0, stream>>>(patch, lib, scal, cand, out);
  pc_map_kernel<<<IMG, 256, 0, stream>>>(minval, out + 1);
}

// Round 7
// 339.034 us; speedup vs baseline: 1.6578x; 1.1375x over previous
//
#include <hip/hip_runtime.h>

#define M_PATCH 676
#define K_DIM   384
#define N_LIB   100000
#define BM      128
#define BN      128
#define NCH     782           // ceil(100000/128)
#define MTILES  6
#define M_PAD   (MTILES*BM)   // 768
#define N_PAD   (NCH*BN)      // 100096
#define XCHUNK  98            // chunks per XCD (8*98 = 784 >= 782)
#define GRID_GEMM (8*XCHUNK*MTILES)   // 4704
#define NTOPB   1563          // ceil(100000/64)
#define NCAND   (NTOPB*3)
#define IMG     224
#define FMAP    26
#define KS      33
#define KHALF   16

typedef __attribute__((ext_vector_type(4))) float  f32x4;
typedef __attribute__((ext_vector_type(8))) short  short8;
typedef unsigned long long ull;

static __device__ __forceinline__ unsigned short f2bf(float f) {
  unsigned u = __float_as_uint(f);
  u = u + 0x7FFFu + ((u >> 16) & 1u);   // RNE; inputs finite
  return (unsigned short)(u >> 16);
}

static __device__ __forceinline__ ull shfl_xor_u64(ull v, int m) {
  unsigned lo = (unsigned)v, hi = (unsigned)(v >> 32);
  lo = __shfl_xor(lo, m, 64);
  hi = __shfl_xor(hi, m, 64);
  return ((ull)hi << 32) | lo;
}

static __device__ __forceinline__ ull umin64(ull a, ull b) { return a < b ? a : b; }
static __device__ __forceinline__ ull umax64(ull a, ull b) { return a > b ? a : b; }
static __device__ __forceinline__ unsigned umin32(unsigned a, unsigned b) { return a < b ? a : b; }

// DPP row_ror:n within 16-lane rows (VALU, no LDS traffic). 0x120+n = row_ror.
#define DPP_ROR_MIN(x, n)                                                              \
  (x) = umin32((x), (unsigned)__builtin_amdgcn_update_dpp((int)(x), (int)(x),          \
                                                          0x120 + (n), 0xF, 0xF, false))

static __device__ __forceinline__ void gld16(const unsigned short* g, unsigned short* l) {
  __builtin_amdgcn_global_load_lds(
      (const __attribute__((address_space(1))) void*)g,
      (__attribute__((address_space(3))) void*)l, 16, 0, 0);
}

// ---------------- K1: row norms + bf16 conversion (float4/float2, 2 rows per wave) -------
// grid: (N_PAD + M_PAD)/8 blocks x 256. Also zero-inits the scal[8] completion counter.
__global__ void pc_norms_cvt_kernel(const float* __restrict__ patch, const float* __restrict__ lib,
                                    float* __restrict__ y2, float* __restrict__ x2,
                                    unsigned short* __restrict__ Abf, unsigned short* __restrict__ Bbf,
                                    unsigned* __restrict__ scal) {
  if (blockIdx.x == 0 && threadIdx.x == 0) scal[8] = 0;
  const int w = threadIdx.x >> 6, lane = threadIdx.x & 63;
  const long rbase = (long)blockIdx.x * 8 + w * 2;
  #pragma unroll
  for (int i = 0; i < 2; ++i) {
    const long r = rbase + i;
    if (r < N_PAD) {
      if (r < N_LIB) {
        const float* src = lib + r * K_DIM;
        const float4 v4 = *(const float4*)(src + lane * 4);
        const float2 v2 = *(const float2*)(src + 256 + lane * 2);
        *(ushort4*)(Bbf + r * K_DIM + lane * 4) =
            make_ushort4(f2bf(v4.x), f2bf(v4.y), f2bf(v4.z), f2bf(v4.w));
        *(ushort2*)(Bbf + r * K_DIM + 256 + lane * 2) = make_ushort2(f2bf(v2.x), f2bf(v2.y));
        float s = v4.x * v4.x + v4.y * v4.y + v4.z * v4.z + v4.w * v4.w
                + v2.x * v2.x + v2.y * v2.y;
        #pragma unroll
        for (int m = 1; m < 64; m <<= 1) s += __shfl_xor(s, m, 64);
        if (lane == 0) y2[r] = s;
      } else {
        *(ushort4*)(Bbf + r * K_DIM + lane * 4) = make_ushort4(0, 0, 0, 0);
        *(ushort2*)(Bbf + r * K_DIM + 256 + lane * 2) = make_ushort2(0, 0);
        if (lane == 0) y2[r] = __builtin_inff();
      }
    } else {
      const long pr = r - N_PAD;
      if (pr < M_PATCH) {
        const float* src = patch + pr * K_DIM;
        const float4 v4 = *(const float4*)(src + lane * 4);
        const float2 v2 = *(const float2*)(src + 256 + lane * 2);
        *(ushort4*)(Abf + pr * K_DIM + lane * 4) =
            make_ushort4(f2bf(v4.x), f2bf(v4.y), f2bf(v4.z), f2bf(v4.w));
        *(ushort2*)(Abf + pr * K_DIM + 256 + lane * 2) = make_ushort2(f2bf(v2.x), f2bf(v2.y));
        float s = v4.x * v4.x + v4.y * v4.y + v4.z * v4.z + v4.w * v4.w
                + v2.x * v2.x + v2.y * v2.y;
        #pragma unroll
        for (int m = 1; m < 64; m <<= 1) s += __shfl_xor(s, m, 64);
        if (lane == 0) x2[pr] = s;
      } else if (pr < M_PAD) {
        *(ushort4*)(Abf + pr * K_DIM + lane * 4) = make_ushort4(0, 0, 0, 0);
        *(ushort2*)(Abf + pr * K_DIM + 256 + lane * 2) = make_ushort2(0, 0);
      }
    }
  }
}

// ---------------- K2: bf16 MFMA GEMM, XCD grid, BK=64, fused min (DPP epilogue) ----------
__launch_bounds__(256, 4)
__global__ void pc_gemm_min_bf16_kernel(const unsigned short* __restrict__ Abf,
                                        const unsigned short* __restrict__ Bbf,
                                        const float* __restrict__ x2g, const float* __restrict__ y2g,
                                        ull* __restrict__ partial) {
  __shared__ unsigned short As[2][BM * 32];
  __shared__ unsigned short Bs[2][BN * 32];
  __shared__ float x2s[BM];
  __shared__ float y2s[BN];
  __shared__ unsigned red32[BM * 2];

  const int l = blockIdx.x;
  const int xcd = l & 7, slot = l >> 3;
  const int chunk = xcd * XCHUNK + slot / MTILES;
  const int mtile = slot % MTILES;
  const int t = threadIdx.x;
  const int m0 = mtile * BM;
  if (chunk >= NCH) {               // pad chunks: write +inf keys (replaces host memset)
    if (t < BM) partial[(size_t)chunk * M_PAD + m0 + t] = ~0ull;
    return;
  }
  const int n0 = chunk * BN;
  const int wid = t >> 6, lane = t & 63;

  if (t < BM) {
    const int gm = m0 + t;
    x2s[t] = (gm < M_PATCH) ? x2g[gm] : 0.f;
    y2s[t] = y2g[n0 + t];
  }

  const int srow   = (wid << 4) + (lane >> 2);
  const int spiece = (lane & 3) ^ ((lane >> 4) & 3);
  const unsigned short* gA0 = Abf + (size_t)(m0 + srow) * K_DIM + spiece * 8;
  const unsigned short* gA1 = gA0 + (size_t)64 * K_DIM;
  const unsigned short* gB0 = Bbf + (size_t)(n0 + srow) * K_DIM + spiece * 8;
  const unsigned short* gB1 = gB0 + (size_t)64 * K_DIM;

  f32x4 acc[4][4];
  #pragma unroll
  for (int i = 0; i < 4; ++i)
    #pragma unroll
    for (int j = 0; j < 4; ++j) acc[i][j] = (f32x4){0.f, 0.f, 0.f, 0.f};

  const int wm = wid >> 1, wn = wid & 1;
  const int quad = lane >> 4, l15 = lane & 15;
  const int poff = (quad ^ ((l15 >> 2) & 3)) * 8;

  for (int ks = 0; ks < K_DIM / 64; ++ks) {
    __syncthreads();
    #pragma unroll
    for (int h = 0; h < 2; ++h) {
      const int ko = ks * 64 + h * 32;
      gld16(gA0 + ko, &As[h][wid * 512]);
      gld16(gA1 + ko, &As[h][(wid + 4) * 512]);
      gld16(gB0 + ko, &Bs[h][wid * 512]);
      gld16(gB1 + ko, &Bs[h][(wid + 4) * 512]);
    }
    __builtin_amdgcn_s_waitcnt(0);
    __syncthreads();

    #pragma unroll
    for (int h = 0; h < 2; ++h) {
      short8 af[4], bf[4];
      #pragma unroll
      for (int mi = 0; mi < 4; ++mi)
        af[mi] = *(const short8*)&As[h][(wm * 64 + mi * 16 + l15) * 32 + poff];
      #pragma unroll
      for (int ni = 0; ni < 4; ++ni)
        bf[ni] = *(const short8*)&Bs[h][(wn * 64 + ni * 16 + l15) * 32 + poff];
      #pragma unroll
      for (int mi = 0; mi < 4; ++mi)
        #pragma unroll
        for (int ni = 0; ni < 4; ++ni)
          acc[mi][ni] = __builtin_amdgcn_mfma_f32_16x16x32_bf16(af[mi], bf[ni], acc[mi][ni], 0, 0, 0);
    }
  }

  // Epilogue: u32 key = (d2bits & ~63) | col6; 16-lane min via DPP row_ror (no LDS ops).
  // Quantization (<=64 ULP of d2~1e3 => ~4e-3) is far below the bf16 dot noise and the
  // 0.5 output threshold; ties resolve to smallest col = reference first-min semantics.
  #pragma unroll
  for (int mi = 0; mi < 4; ++mi) {
    #pragma unroll
    for (int r = 0; r < 4; ++r) {
      const int row_l = wm * 64 + mi * 16 + quad * 4 + r;
      const float xs = x2s[row_l];
      unsigned kmin = 0xFFFFFFFFu;
      #pragma unroll
      for (int ni = 0; ni < 4; ++ni) {
        const int col_l = wn * 64 + ni * 16 + l15;
        float d2 = xs + y2s[col_l] - 2.0f * acc[mi][ni][r];
        d2 = fmaxf(d2, 0.0f);
        const unsigned key = (__float_as_uint(d2) & 0xFFFFFFC0u) | (unsigned)(ni * 16 + l15);
        kmin = umin32(kmin, key);
      }
      DPP_ROR_MIN(kmin, 8);
      DPP_ROR_MIN(kmin, 4);
      DPP_ROR_MIN(kmin, 2);
      DPP_ROR_MIN(kmin, 1);
      if (l15 == 0) red32[row_l * 2 + wn] = kmin;
    }
  }
  __syncthreads();
  if (t < BM) {
    const unsigned v0 = red32[t * 2], v1 = red32[t * 2 + 1];
    const ull k0 = ((ull)(v0 & 0xFFFFFFC0u) << 32) | (unsigned)(n0 + (v0 & 63u));
    const ull k1 = ((ull)(v1 & 0xFFFFFFC0u) << 32) | (unsigned)(n0 + 64 + (v1 & 63u));
    partial[(size_t)chunk * M_PAD + m0 + t] = umin64(k0, k1);
  }
}

// ---------------- K3: partial reduce (48 blocks) + last-block select ---------------------
__global__ void pc_reduce_kernel(const ull* __restrict__ partial, ull* __restrict__ stage1,
                                 float* __restrict__ minval, unsigned* __restrict__ minidx,
                                 unsigned* __restrict__ scal) {
  const int b = blockIdx.x, mt = b >> 3, gp = b & 7;
  const int t = threadIdx.x;           // 128
  const int c0 = gp * XCHUNK;
  ull k = ~0ull;
  #pragma unroll 7
  for (int i = 0; i < XCHUNK; ++i)
    k = umin64(k, partial[(size_t)(c0 + i) * M_PAD + mt * 128 + t]);
  stage1[(size_t)(mt * 128 + t) * 8 + gp] = k;
  __threadfence();
  __syncthreads();
  __shared__ unsigned rank_s;
  if (t == 0) rank_s = atomicAdd(&scal[8], 1u);
  __syncthreads();
  if (rank_s != 47) return;
  __threadfence();

  ull best = 0ull;
  for (int m = t; m < M_PATCH; m += 128) {
    ull kk = ~0ull;
    #pragma unroll
    for (int g = 0; g < 8; ++g) kk = umin64(kk, stage1[(size_t)m * 8 + g]);
    const float d = sqrtf(fmaxf(__uint_as_float((unsigned)(kk >> 32)), 0.f));
    minval[m] = d;
    minidx[m] = (unsigned)kk;
    best = umax64(best, ((ull)__float_as_uint(d) << 32) | (0xFFFFFFFFu - (unsigned)m));
  }
  #pragma unroll
  for (int off = 1; off < 64; off <<= 1) best = umax64(best, shfl_xor_u64(best, off));
  __shared__ ull sh[2];
  if ((t & 63) == 0) sh[t >> 6] = best;
  __syncthreads();
  if (t == 0) {
    best = umax64(sh[0], sh[1]);
    const unsigned m = 0xFFFFFFFFu - (unsigned)best;
    scal[0] = m;                      // s_idx
    scal[1] = (unsigned)(best >> 32); // s_star bits
    scal[2] = minidx[m];              // m_star row
  }
}

// ---------------- K4: bf16 GEMV w_dist^2 scan, 4-row ILP batches + wave top-3 ------------
__global__ void pc_wdist_scan_kernel(const unsigned short* __restrict__ Bbf,
                                     const float* __restrict__ y2,
                                     const unsigned* __restrict__ scal,
                                     ull* __restrict__ cand) {
  __shared__ ull keys[64];
  const int t = threadIdx.x, w = t >> 6, lane = t & 63;
  const unsigned star = scal[2];
  const float y2star = y2[star];
  const unsigned* msp = (const unsigned*)(Bbf + (size_t)star * K_DIM);
  float msl[3], msh[3];
  #pragma unroll
  for (int j = 0; j < 3; ++j) {
    const unsigned u = msp[lane + 64 * j];
    msl[j] = __uint_as_float(u << 16);
    msh[j] = __uint_as_float(u & 0xFFFF0000u);
  }
  const long r0 = (long)blockIdx.x * 64 + w * 16;
  #pragma unroll
  for (int b = 0; b < 4; ++b) {
    const long rb = r0 + b * 4;
    unsigned u[4][3];
    #pragma unroll
    for (int i = 0; i < 4; ++i) {
      const long r = rb + i;
      const unsigned* p = (const unsigned*)(Bbf + (size_t)(r < N_LIB ? r : 0) * K_DIM);
      #pragma unroll
      for (int j = 0; j < 3; ++j) u[i][j] = p[lane + 64 * j];
    }
    float s[4];
    #pragma unroll
    for (int i = 0; i < 4; ++i) {
      s[i] = 0.f;
      #pragma unroll
      for (int j = 0; j < 3; ++j)
        s[i] += msl[j] * __uint_as_float(u[i][j] << 16)
              + msh[j] * __uint_as_float(u[i][j] & 0xFFFF0000u);
    }
    #pragma unroll
    for (int m = 1; m < 64; m <<= 1) {
      #pragma unroll
      for (int i = 0; i < 4; ++i) s[i] += __shfl_xor(s[i], m, 64);
    }
    if (lane == 0) {
      #pragma unroll
      for (int i = 0; i < 4; ++i) {
        const long r = rb + i;
        const float d2 = fmaxf(y2star + y2[r] - 2.0f * s[i], 0.0f);
        keys[w * 16 + b * 4 + i] =
            (r < N_LIB) ? (((ull)__float_as_uint(d2) << 32) | (unsigned)r) : ~0ull;
      }
    }
  }
  __syncthreads();
  if (w == 0) {    // wave-parallel 3-pass first-min top-3 over the 64 block keys
    const ull k0 = keys[lane];
    ull p0, p1, k;
    k = k0;
    #pragma unroll
    for (int off = 1; off < 64; off <<= 1) k = umin64(k, shfl_xor_u64(k, off));
    p0 = k;
    k = (k0 == p0) ? ~0ull : k0;
    #pragma unroll
    for (int off = 1; off < 64; off <<= 1) k = umin64(k, shfl_xor_u64(k, off));
    p1 = k;
    k = (k0 == p0 || k0 == p1) ? ~0ull : k0;
    #pragma unroll
    for (int off = 1; off < 64; off <<= 1) k = umin64(k, shfl_xor_u64(k, off));
    if (lane == 0) {
      cand[(long)blockIdx.x * 3 + 0] = p0;
      cand[(long)blockIdx.x * 3 + 1] = p1;
      cand[(long)blockIdx.x * 3 + 2] = k;
    }
  }
}

// ---------------- K5: merge candidates (first-min top-3) + exact dists + score -----------
__global__ void pc_merge_final_kernel(const float* __restrict__ patch, const float* __restrict__ lib,
                                      const unsigned* __restrict__ scal, const ull* __restrict__ cand,
                                      float* __restrict__ out) {
  __shared__ ull shm[16];
  __shared__ ull picks_s[3];
  const int t = threadIdx.x, w = t >> 6, lane = t & 63;  // 1024 threads
  for (int p = 0; p < 3; ++p) {
    const ull e0 = (p > 0) ? picks_s[0] : 0ull;
    const ull e1 = (p > 1) ? picks_s[1] : 0ull;
    ull k = ~0ull;
    for (int n = t; n < NCAND; n += 1024) {
      const ull c = cand[n];
      if ((p > 0 && c == e0) || (p > 1 && c == e1)) continue;
      k = umin64(k, c);
    }
    #pragma unroll
    for (int off = 1; off < 64; off <<= 1) k = umin64(k, shfl_xor_u64(k, off));
    if ((t & 63) == 0) shm[t >> 6] = k;
    __syncthreads();
    if (t == 0) {
      #pragma unroll
      for (int ww = 1; ww < 16; ++ww) k = umin64(k, shm[ww]);
      picks_s[p] = k;
    }
    __syncthreads();
  }
  // exact fp32 distances m_test vs the 2nd/3rd neighbors
  __shared__ float sh2[2];
  if (w < 2) {
    const unsigned nn = (unsigned)picks_s[1 + w];
    const float* mt2 = patch + (size_t)scal[0] * K_DIM;
    const float* pv  = lib + (size_t)nn * K_DIM;
    float s = 0.f;
    #pragma unroll
    for (int j = 0; j < 6; ++j) { const float d = mt2[lane + 64 * j] - pv[lane + 64 * j]; s += d * d; }
    #pragma unroll
    for (int m = 1; m < 64; m <<= 1) s += __shfl_xor(s, m, 64);
    if (lane == 0) sh2[w] = s;
  }
  __syncthreads();
  if (t == 0) {
    const float D = sqrtf((float)K_DIM);
    const float s_star = __uint_as_float(scal[1]);
    const float a = sqrtf(sh2[0]), b = sqrtf(sh2[1]);
    const float wgt = 1.f - expf(s_star / D) / (expf(a / D) + expf(b / D));
    out[0] = wgt * s_star;
  }
}

// ---------------- K6: fused bilinear 26->224 + separable 33-tap gaussian -----------------
static __device__ __forceinline__ int pc_refl(int i) {
  return i < 0 ? -i : (i >= IMG ? 2 * IMG - 2 - i : i);
}

__global__ void pc_map_kernel(const float* __restrict__ minval, float* __restrict__ outmap) {
  __shared__ double kd[KS + 1];
  __shared__ float kf[KS];
  __shared__ float smap[FMAP * FMAP];
  __shared__ float by[IMG];
  const int t = threadIdx.x;          // 256
  const int y = blockIdx.x;           // 224
  if (t < KS) { const double xx = (double)(t - KHALF) / 4.0; kd[t] = exp(-0.5 * xx * xx); }
  for (int i = t; i < FMAP * FMAP; i += 256) smap[i] = minval[i];
  __syncthreads();
  if (t == 0) { double s = 0.0; for (int i = 0; i < KS; ++i) s += kd[i]; kd[KS] = s; }
  __syncthreads();
  if (t < KS) kf[t] = (float)(kd[t] / kd[KS]);
  __syncthreads();

  const float scale = (float)FMAP / (float)IMG;
  if (t < IMG) {
    const float fx = ((float)t + 0.5f) * scale - 0.5f;
    const int ix0 = (int)floorf(fx); const float tx = fx - (float)ix0;
    const int x0 = min(max(ix0, 0), FMAP - 1), x1 = min(max(ix0 + 1, 0), FMAP - 1);
    float s = 0.f;
    #pragma unroll
    for (int j = 0; j < KS; ++j) {
      const int yy = pc_refl(y + j - KHALF);
      const float fy = ((float)yy + 0.5f) * scale - 0.5f;
      const int iy0 = (int)floorf(fy); const float ty = fy - (float)iy0;
      const int y0 = min(max(iy0, 0), FMAP - 1), y1 = min(max(iy0 + 1, 0), FMAP - 1);
      const float v00 = smap[y0 * FMAP + x0], v01 = smap[y0 * FMAP + x1];
      const float v10 = smap[y1 * FMAP + x0], v11 = smap[y1 * FMAP + x1];
      const float v0 = v00 + (v01 - v00) * tx;
      const float v1 = v10 + (v11 - v10) * tx;
      s += kf[j] * (v0 + (v1 - v0) * ty);
    }
    by[t] = s;
  }
  __syncthreads();
  if (t < IMG) {
    float s = 0.f;
    #pragma unroll
    for (int i = 0; i < KS; ++i) s += kf[i] * by[pc_refl(t + i - KHALF)];
    outmap[y * IMG + t] = s;
  }
}

extern "C" void kernel_launch(void* const* d_in, const int* in_sizes, int n_in,
                              void* d_out, int out_size, void* d_ws, size_t ws_size,
                              hipStream_t stream) {
  const float* patch = (const float*)d_in[0];
  const float* lib   = (const float*)d_in[1];
  float* out = (float*)d_out;

  char* p = (char*)d_ws;
  auto take = [&](size_t n) { char* q = p; p += (n + 511) & ~(size_t)511; return q; };
  float* y2        = (float*)take((size_t)N_PAD * 4);
  float* x2        = (float*)take((size_t)M_PAD * 4);
  ull* partial     = (ull*)take((size_t)(NCH + 2) * M_PAD * 8);   // +2 pad chunks (gemm-inited)
  ull* stage1      = (ull*)take((size_t)M_PAD * 8 * 8);
  float* minval    = (float*)take((size_t)M_PATCH * 4);
  unsigned* minidx = (unsigned*)take((size_t)M_PATCH * 4);
  unsigned* scal   = (unsigned*)take(256);                        // [0..7] results, [8] counter
  ull* cand        = (ull*)take((size_t)NCAND * 8);
  unsigned short* Abf = (unsigned short*)take((size_t)M_PAD * K_DIM * 2);
  unsigned short* Bbf = (unsigned short*)take((size_t)N_PAD * K_DIM * 2);
  (void)in_sizes; (void)n_in; (void)out_size; (void)ws_size;

  const int norm_rows = N_PAD + M_PAD;  // 100864, /8 = 12608 blocks
  pc_norms_cvt_kernel<<<norm_rows / 8, 256, 0, stream>>>(patch, lib, y2, x2, Abf, Bbf, scal);
  pc_gemm_min_bf16_kernel<<<GRID_GEMM, 256, 0, stream>>>(Abf, Bbf, x2, y2, partial);
  pc_reduce_kernel<<<48, 128, 0, stream>>>(partial, stage1, minval, minidx, scal);
  pc_wdist_scan_kernel<<<NTOPB, 256, 0, stream>>>(Bbf, y2, scal, cand);
  pc_merge_final_kernel<<<1, 1024, 0, stream>>>(patch, lib, scal, cand, out);
  pc_map_kernel<<<IMG, 256, 0, stream>>>(minval, out + 1);
}